// Round 2
// baseline (3048.904 us; speedup 1.0000x reference)
//
#include <hip/hip_runtime.h>
#include <math.h>

#define D 256
#define BM 64
#define BK 32
#define EPS 1e-12f

// ---------------- zero workspace ----------------
__global__ void zero_kernel(float* __restrict__ a, size_t na4,
                            float* __restrict__ b, size_t nb) {
    size_t i = (size_t)blockIdx.x * blockDim.x + threadIdx.x;
    size_t stride = (size_t)gridDim.x * blockDim.x;
    float4* a4 = (float4*)a;
    float4 z = make_float4(0.f, 0.f, 0.f, 0.f);
    for (size_t k = i; k < na4; k += stride) a4[k] = z;
    for (size_t k = i; k < nb; k += stride) b[k] = 0.f;
}

// ---------------- edge scatter: one wave per edge ----------------
// lane l handles floats [4l, 4l+4) of the 256-wide row: full row per wave.
__global__ void scatter_kernel(const float* __restrict__ x,
                               const int* __restrict__ adj,
                               float* __restrict__ acc,
                               float* __restrict__ deg,
                               int E) {
    int wavesPerBlock = blockDim.x >> 6;
    int wave = blockIdx.x * wavesPerBlock + (threadIdx.x >> 6);
    int lane = threadIdx.x & 63;
    int nw = gridDim.x * wavesPerBlock;
    for (int e = wave; e < E; e += nw) {
        int src = adj[e];
        int dst = adj[E + e];
        float4 v = *(const float4*)(x + (size_t)src * D + lane * 4);
        float* p = acc + (size_t)dst * D + lane * 4;
        atomicAdd(p + 0, v.x);
        atomicAdd(p + 1, v.y);
        atomicAdd(p + 2, v.z);
        atomicAdd(p + 3, v.w);
        if (lane == 0) atomicAdd(deg + dst, 1.0f);
    }
}

// ---------------- fused mean + concat-GEMM + bias + relu + L2 norm ----------
// Block: 256 threads, tile BM=64 rows x 256 cols (full width), K = 512.
// Thread (ty = t>>4, tx = t&15): rows ty*4..ty*4+3, cols {j2*64 + tx*4 + j}.
__global__ __launch_bounds__(256) void gemm_kernel(
        const float* __restrict__ x,
        const float* __restrict__ acc,
        const float* __restrict__ W,
        const float* __restrict__ bias,
        const float* __restrict__ deg,
        float* __restrict__ out,
        int N) {
    __shared__ float Ast[BK][BM];     // A tile transposed: Ast[k][row]
    __shared__ float Ws[BK][D];       // W tile: Ws[k][col]
    __shared__ float invdeg_s[BM];

    int t = threadIdx.x;
    int row0 = blockIdx.x * BM;

    if (t < BM) {
        int r = row0 + t;
        float dg = (r < N) ? deg[r] : 1.0f;
        invdeg_s[t] = 1.0f / fmaxf(dg, 1.0f);
    }

    int tx = t & 15;
    int ty = t >> 4;

    float accr[4][16];
#pragma unroll
    for (int i = 0; i < 4; i++)
#pragma unroll
        for (int j = 0; j < 16; j++) accr[i][j] = 0.f;

    // A loader: thread covers rows {arow, arow+32}, k-span akv*4..akv*4+3
    int arow = t >> 3;   // 0..31
    int akv = t & 7;     // 0..7
    // W loader: thread covers float4 col wc, k rows wk0 + 4*kk
    int wc = t & 63;     // 0..63
    int wk0 = t >> 6;    // 0..3

    for (int k0 = 0; k0 < 2 * D; k0 += BK) {
        __syncthreads();  // prev-iter LDS reads done (also covers invdeg_s)
#pragma unroll
        for (int rr = 0; rr < 2; rr++) {
            int rl = arow + rr * 32;
            int gr = row0 + rl;
            int grc = gr < N ? gr : N - 1;
            float4 v;
            if (k0 < D) {
                v = *(const float4*)(x + (size_t)grc * D + k0 + akv * 4);
            } else {
                v = *(const float4*)(acc + (size_t)grc * D + (k0 - D) + akv * 4);
                float s = invdeg_s[rl];
                v.x *= s; v.y *= s; v.z *= s; v.w *= s;
            }
            Ast[akv * 4 + 0][rl] = v.x;
            Ast[akv * 4 + 1][rl] = v.y;
            Ast[akv * 4 + 2][rl] = v.z;
            Ast[akv * 4 + 3][rl] = v.w;
        }
#pragma unroll
        for (int kk = 0; kk < 8; kk++) {
            int kr = wk0 + kk * 4;
            float4 wv = *(const float4*)(W + (size_t)(k0 + kr) * D + wc * 4);
            *(float4*)(&Ws[kr][wc * 4]) = wv;
        }
        __syncthreads();
#pragma unroll
        for (int k = 0; k < BK; k++) {
            float4 a4 = *(const float4*)(&Ast[k][ty * 4]);
            float av[4] = {a4.x, a4.y, a4.z, a4.w};
#pragma unroll
            for (int j2 = 0; j2 < 4; j2++) {
                float4 w4 = *(const float4*)(&Ws[k][j2 * 64 + tx * 4]);
                float wv[4] = {w4.x, w4.y, w4.z, w4.w};
#pragma unroll
                for (int i = 0; i < 4; i++)
#pragma unroll
                    for (int j = 0; j < 4; j++)
                        accr[i][j2 * 4 + j] += av[i] * wv[j];
            }
        }
    }

    // epilogue: bias + relu + row L2 norm + store
    float bval[16];
#pragma unroll
    for (int j2 = 0; j2 < 4; j2++) {
        float4 b4 = *(const float4*)(bias + j2 * 64 + tx * 4);
        bval[j2 * 4 + 0] = b4.x;
        bval[j2 * 4 + 1] = b4.y;
        bval[j2 * 4 + 2] = b4.z;
        bval[j2 * 4 + 3] = b4.w;
    }
#pragma unroll
    for (int i = 0; i < 4; i++) {
        float ss = 0.f;
#pragma unroll
        for (int j = 0; j < 16; j++) {
            float v = accr[i][j] + bval[j];
            v = fmaxf(v, 0.f);
            accr[i][j] = v;
            ss += v * v;
        }
        // reduce across the 16 tx lanes (contiguous within the wave)
        ss += __shfl_xor(ss, 1);
        ss += __shfl_xor(ss, 2);
        ss += __shfl_xor(ss, 4);
        ss += __shfl_xor(ss, 8);
        float inv = 1.0f / fmaxf(sqrtf(ss), EPS);
        int gr = row0 + ty * 4 + i;
        if (gr < N) {
#pragma unroll
            for (int j2 = 0; j2 < 4; j2++) {
                float4 o;
                o.x = accr[i][j2 * 4 + 0] * inv;
                o.y = accr[i][j2 * 4 + 1] * inv;
                o.z = accr[i][j2 * 4 + 2] * inv;
                o.w = accr[i][j2 * 4 + 3] * inv;
                *(float4*)(out + (size_t)gr * D + j2 * 64 + tx * 4) = o;
            }
        }
    }
}

extern "C" void kernel_launch(void* const* d_in, const int* in_sizes, int n_in,
                              void* d_out, int out_size, void* d_ws, size_t ws_size,
                              hipStream_t stream) {
    const float* x = (const float*)d_in[0];
    const int* adj = (const int*)d_in[1];
    const float* W = (const float*)d_in[2];
    const float* b = (const float*)d_in[3];
    float* out = (float*)d_out;

    int N = in_sizes[0] / D;    // 50000
    int E = in_sizes[1] / 2;    // 800000

    size_t accBytes = (size_t)N * D * sizeof(float);
    size_t degBytes = (size_t)N * sizeof(float);

    float* acc;
    float* deg;
    if (ws_size >= accBytes + degBytes) {
        acc = (float*)d_ws;
        deg = (float*)((char*)d_ws + accBytes);
    } else {
        // fallback: accumulate neighbor sums directly in d_out (each GEMM block
        // reads only rows it later overwrites — safe), deg in ws.
        acc = (float*)d_out;
        deg = (float*)d_ws;
    }

    zero_kernel<<<2048, 256, 0, stream>>>(acc, (size_t)N * D / 4, deg, (size_t)N);
    scatter_kernel<<<2048, 256, 0, stream>>>(x, adj, acc, deg, E);
    int gb = (N + BM - 1) / BM;
    gemm_kernel<<<gb, 256, 0, stream>>>(x, acc, W, b, deg, out, N);
}

// Round 4
// 576.820 us; speedup vs baseline: 5.2857x; 5.2857x over previous
//
#include <hip/hip_runtime.h>
#include <math.h>

#define D 256
#define BM 64
#define BK 32
#define EPS 1e-12f

// ---------------- zero int array ----------------
__global__ void zero_ints(int* __restrict__ p, int n) {
    int i = blockIdx.x * blockDim.x + threadIdx.x;
    if (i < n) p[i] = 0;
}

// ---------------- degree histogram ----------------
__global__ void hist_kernel(const int* __restrict__ adj, int* __restrict__ deg, int E) {
    int i = blockIdx.x * blockDim.x + threadIdx.x;
    int stride = gridDim.x * blockDim.x;
    for (int e = i; e < E; e += stride) atomicAdd(&deg[adj[E + e]], 1);
}

// ---------------- single-block exclusive scan over N degrees ----------------
__global__ __launch_bounds__(1024) void scan_kernel(const int* __restrict__ deg,
                                                    int* __restrict__ offs,
                                                    int* __restrict__ cursor,
                                                    int N, int E) {
    __shared__ int buf[1024];
    __shared__ int running_s;
    int t = threadIdx.x;
    if (t == 0) running_s = 0;
    __syncthreads();
    for (int base = 0; base < N; base += 1024) {
        int i = base + t;
        int v = (i < N) ? deg[i] : 0;
        buf[t] = v;
        __syncthreads();
#pragma unroll
        for (int off = 1; off < 1024; off <<= 1) {
            int add = (t >= off) ? buf[t - off] : 0;
            __syncthreads();
            buf[t] += add;
            __syncthreads();
        }
        int incl = buf[t];
        int run = running_s;
        if (i < N) {
            int excl = run + incl - v;
            offs[i] = excl;
            cursor[i] = excl;
        }
        __syncthreads();
        if (t == 1023) running_s = run + incl;
        __syncthreads();
    }
    if (t == 0) offs[N] = E;
}

// ---------------- CSR fill ----------------
__global__ void fill_kernel(const int* __restrict__ adj, int* __restrict__ cursor,
                            int* __restrict__ csr, int E) {
    int i = blockIdx.x * blockDim.x + threadIdx.x;
    int stride = gridDim.x * blockDim.x;
    for (int e = i; e < E; e += stride) {
        int src = adj[e];
        int dst = adj[E + e];
        int pos = atomicAdd(&cursor[dst], 1);
        csr[pos] = src;
    }
}

// ---------------- gather + mean: one wave per destination node ----------------
__global__ __launch_bounds__(256) void gather_kernel(const float* __restrict__ x,
                                                     const int* __restrict__ offs,
                                                     const int* __restrict__ csr,
                                                     float* __restrict__ acc, int N) {
    int wv = blockIdx.x * (blockDim.x >> 6) + (threadIdx.x >> 6);
    wv = __builtin_amdgcn_readfirstlane(wv);
    if (wv >= N) return;
    int lane = threadIdx.x & 63;
    int beg = offs[wv];
    int end = offs[wv + 1];
    const float* xp = x + (size_t)lane * 4;
    float4 s = make_float4(0.f, 0.f, 0.f, 0.f);
    int j = beg;
    for (; j + 4 <= end; j += 4) {
        int n0 = csr[j + 0];
        int n1 = csr[j + 1];
        int n2 = csr[j + 2];
        int n3 = csr[j + 3];
        float4 v0 = *(const float4*)(xp + (size_t)n0 * D);
        float4 v1 = *(const float4*)(xp + (size_t)n1 * D);
        float4 v2 = *(const float4*)(xp + (size_t)n2 * D);
        float4 v3 = *(const float4*)(xp + (size_t)n3 * D);
        s.x += (v0.x + v1.x) + (v2.x + v3.x);
        s.y += (v0.y + v1.y) + (v2.y + v3.y);
        s.z += (v0.z + v1.z) + (v2.z + v3.z);
        s.w += (v0.w + v1.w) + (v2.w + v3.w);
    }
    for (; j < end; ++j) {
        int n0 = csr[j];
        float4 v0 = *(const float4*)(xp + (size_t)n0 * D);
        s.x += v0.x; s.y += v0.y; s.z += v0.z; s.w += v0.w;
    }
    float inv = 1.0f / fmaxf((float)(end - beg), 1.0f);
    s.x *= inv; s.y *= inv; s.z *= inv; s.w *= inv;
    *(float4*)(acc + (size_t)wv * D + lane * 4) = s;
}

// ---------------- fused concat-GEMM + bias + relu + L2 norm ----------
// Block: 256 threads, tile BM=64 rows x 256 cols (full width), K = 512.
// Thread (ty = t>>4, tx = t&15): rows ty*4..ty*4+3, cols {j2*64 + tx*4 + j}.
__global__ __launch_bounds__(256) void gemm_kernel(
        const float* __restrict__ x,
        const float* __restrict__ acc,
        const float* __restrict__ W,
        const float* __restrict__ bias,
        float* __restrict__ out,
        int N) {
    __shared__ float Ast[BK][BM];     // A tile transposed: Ast[k][row]
    __shared__ float Ws[BK][D];       // W tile: Ws[k][col]

    int t = threadIdx.x;
    int row0 = blockIdx.x * BM;

    int tx = t & 15;
    int ty = t >> 4;

    float accr[4][16];
#pragma unroll
    for (int i = 0; i < 4; i++)
#pragma unroll
        for (int j = 0; j < 16; j++) accr[i][j] = 0.f;

    // A loader: thread covers rows {arow, arow+32}, k-span akv*4..akv*4+3
    int arow = t >> 3;   // 0..31
    int akv = t & 7;     // 0..7
    // W loader: thread covers float4 col wc, k rows wk0 + 4*kk
    int wc = t & 63;     // 0..63
    int wk0 = t >> 6;    // 0..3

    for (int k0 = 0; k0 < 2 * D; k0 += BK) {
        __syncthreads();  // prev-iter LDS reads done
#pragma unroll
        for (int rr = 0; rr < 2; rr++) {
            int rl = arow + rr * 32;
            int gr = row0 + rl;
            int grc = gr < N ? gr : N - 1;
            float4 v;
            if (k0 < D) {
                v = *(const float4*)(x + (size_t)grc * D + k0 + akv * 4);
            } else {
                v = *(const float4*)(acc + (size_t)grc * D + (k0 - D) + akv * 4);
            }
            Ast[akv * 4 + 0][rl] = v.x;
            Ast[akv * 4 + 1][rl] = v.y;
            Ast[akv * 4 + 2][rl] = v.z;
            Ast[akv * 4 + 3][rl] = v.w;
        }
#pragma unroll
        for (int kk = 0; kk < 8; kk++) {
            int kr = wk0 + kk * 4;
            float4 wv = *(const float4*)(W + (size_t)(k0 + kr) * D + wc * 4);
            *(float4*)(&Ws[kr][wc * 4]) = wv;
        }
        __syncthreads();
#pragma unroll
        for (int k = 0; k < BK; k++) {
            float4 a4 = *(const float4*)(&Ast[k][ty * 4]);
            float av[4] = {a4.x, a4.y, a4.z, a4.w};
#pragma unroll
            for (int j2 = 0; j2 < 4; j2++) {
                float4 w4 = *(const float4*)(&Ws[k][j2 * 64 + tx * 4]);
                float wv[4] = {w4.x, w4.y, w4.z, w4.w};
#pragma unroll
                for (int i = 0; i < 4; i++)
#pragma unroll
                    for (int j = 0; j < 4; j++)
                        accr[i][j2 * 4 + j] += av[i] * wv[j];
            }
        }
    }

    // epilogue: bias + relu + row L2 norm + store
    float bval[16];
#pragma unroll
    for (int j2 = 0; j2 < 4; j2++) {
        float4 b4 = *(const float4*)(bias + j2 * 64 + tx * 4);
        bval[j2 * 4 + 0] = b4.x;
        bval[j2 * 4 + 1] = b4.y;
        bval[j2 * 4 + 2] = b4.z;
        bval[j2 * 4 + 3] = b4.w;
    }
#pragma unroll
    for (int i = 0; i < 4; i++) {
        float ss = 0.f;
#pragma unroll
        for (int j = 0; j < 16; j++) {
            float v = accr[i][j] + bval[j];
            v = fmaxf(v, 0.f);
            accr[i][j] = v;
            ss += v * v;
        }
        // reduce across the 16 tx lanes (contiguous within the wave)
        ss += __shfl_xor(ss, 1);
        ss += __shfl_xor(ss, 2);
        ss += __shfl_xor(ss, 4);
        ss += __shfl_xor(ss, 8);
        float inv = 1.0f / fmaxf(sqrtf(ss), EPS);
        int gr = row0 + ty * 4 + i;
        if (gr < N) {
#pragma unroll
            for (int j2 = 0; j2 < 4; j2++) {
                float4 o;
                o.x = accr[i][j2 * 4 + 0] * inv;
                o.y = accr[i][j2 * 4 + 1] * inv;
                o.z = accr[i][j2 * 4 + 2] * inv;
                o.w = accr[i][j2 * 4 + 3] * inv;
                *(float4*)(out + (size_t)gr * D + j2 * 64 + tx * 4) = o;
            }
        }
    }
}

// ---------------- legacy atomic fallback (only if ws too small) ----------------
__global__ void zero_floats(float* __restrict__ a, size_t n4) {
    size_t i = (size_t)blockIdx.x * blockDim.x + threadIdx.x;
    size_t stride = (size_t)gridDim.x * blockDim.x;
    float4* a4 = (float4*)a;
    float4 z = make_float4(0.f, 0.f, 0.f, 0.f);
    for (size_t k = i; k < n4; k += stride) a4[k] = z;
}

__global__ void scatter_kernel(const float* __restrict__ x, const int* __restrict__ adj,
                               float* __restrict__ acc, float* __restrict__ deg, int E) {
    int wave = blockIdx.x * (blockDim.x >> 6) + (threadIdx.x >> 6);
    int lane = threadIdx.x & 63;
    int nw = gridDim.x * (blockDim.x >> 6);
    for (int e = wave; e < E; e += nw) {
        int src = adj[e];
        int dst = adj[E + e];
        float4 v = *(const float4*)(x + (size_t)src * D + lane * 4);
        float* p = acc + (size_t)dst * D + lane * 4;
        atomicAdd(p + 0, v.x);
        atomicAdd(p + 1, v.y);
        atomicAdd(p + 2, v.z);
        atomicAdd(p + 3, v.w);
        if (lane == 0) atomicAdd(deg + dst, 1.0f);
    }
}

__global__ void mean_kernel(float* __restrict__ acc, const float* __restrict__ deg, int N) {
    int wv = blockIdx.x * (blockDim.x >> 6) + (threadIdx.x >> 6);
    if (wv >= N) return;
    int lane = threadIdx.x & 63;
    float inv = 1.0f / fmaxf(deg[wv], 1.0f);
    float4* p = (float4*)(acc + (size_t)wv * D) + lane;
    float4 v = *p;
    v.x *= inv; v.y *= inv; v.z *= inv; v.w *= inv;
    *p = v;
}

extern "C" void kernel_launch(void* const* d_in, const int* in_sizes, int n_in,
                              void* d_out, int out_size, void* d_ws, size_t ws_size,
                              hipStream_t stream) {
    const float* x = (const float*)d_in[0];
    const int* adj = (const int*)d_in[1];
    const float* W = (const float*)d_in[2];
    const float* b = (const float*)d_in[3];
    float* out = (float*)d_out;

    int N = in_sizes[0] / D;    // 50000
    int E = in_sizes[1] / 2;    // 800000

    size_t accBytes = (size_t)N * D * sizeof(float);
    size_t intBytes = (size_t)(3 * N + 1 + E) * sizeof(int);

    int gb = (N + BM - 1) / BM;
    int gatherBlocks = (N + 3) / 4;

    if (ws_size >= accBytes + intBytes) {
        float* acc = (float*)d_ws;
        int* deg = (int*)((char*)d_ws + accBytes);
        int* offs = deg + N;          // N+1 entries
        int* cursor = offs + N + 1;
        int* csr = cursor + N;
        zero_ints<<<(N + 255) / 256, 256, 0, stream>>>(deg, N);
        hist_kernel<<<1024, 256, 0, stream>>>(adj, deg, E);
        scan_kernel<<<1, 1024, 0, stream>>>(deg, offs, cursor, N, E);
        fill_kernel<<<1024, 256, 0, stream>>>(adj, cursor, csr, E);
        gather_kernel<<<gatherBlocks, 256, 0, stream>>>(x, offs, csr, acc, N);
        gemm_kernel<<<gb, 256, 0, stream>>>(x, acc, W, b, out, N);
    } else if (ws_size >= intBytes) {
        // acc lives in d_out (each GEMM block reads only rows it later writes)
        float* acc = (float*)d_out;
        int* deg = (int*)d_ws;
        int* offs = deg + N;
        int* cursor = offs + N + 1;
        int* csr = cursor + N;
        zero_ints<<<(N + 255) / 256, 256, 0, stream>>>(deg, N);
        hist_kernel<<<1024, 256, 0, stream>>>(adj, deg, E);
        scan_kernel<<<1, 1024, 0, stream>>>(deg, offs, cursor, N, E);
        fill_kernel<<<1024, 256, 0, stream>>>(adj, cursor, csr, E);
        gather_kernel<<<gatherBlocks, 256, 0, stream>>>(x, offs, csr, acc, N);
        gemm_kernel<<<gb, 256, 0, stream>>>(x, acc, W, b, out, N);
    } else {
        // last-resort atomic path
        float* acc = (float*)d_out;
        float* deg = (float*)d_ws;
        zero_floats<<<2048, 256, 0, stream>>>(acc, (size_t)N * D / 4);
        zero_floats<<<64, 256, 0, stream>>>(deg, (size_t)N / 4);
        scatter_kernel<<<2048, 256, 0, stream>>>(x, adj, acc, deg, E);
        mean_kernel<<<gatherBlocks, 256, 0, stream>>>(acc, deg, N);
        gemm_kernel<<<gb, 256, 0, stream>>>(x, acc, W, b, out, N);
    }
}

// Round 5
// 372.653 us; speedup vs baseline: 8.1816x; 1.5479x over previous
//
#include <hip/hip_runtime.h>
#include <math.h>

#define D 256
#define EPS 1e-12f

typedef __attribute__((ext_vector_type(8))) short bf16x8;
typedef __attribute__((ext_vector_type(4))) float f32x4;

// ---- fp32 -> bf16 split helpers (RNE) ----
__device__ __forceinline__ unsigned short f2bf(float f) {
    unsigned int u = __builtin_bit_cast(unsigned int, f);
    unsigned int r = u + 0x7fffu + ((u >> 16) & 1u);
    return (unsigned short)(r >> 16);
}
__device__ __forceinline__ float bf2f(unsigned short s) {
    unsigned int u = ((unsigned int)s) << 16;
    return __builtin_bit_cast(float, u);
}

// ---------------- zero int array ----------------
__global__ void zero_ints(int* __restrict__ p, int n) {
    int i = blockIdx.x * blockDim.x + threadIdx.x;
    if (i < n) p[i] = 0;
}

// ---------------- degree histogram ----------------
__global__ void hist_kernel(const int* __restrict__ adj, int* __restrict__ deg, int E) {
    int i = blockIdx.x * blockDim.x + threadIdx.x;
    int stride = gridDim.x * blockDim.x;
    for (int e = i; e < E; e += stride) atomicAdd(&deg[adj[E + e]], 1);
}

// ---------------- multi-block scan: local inclusive ----------------
__global__ __launch_bounds__(1024) void scan_local(const int* __restrict__ deg,
                                                   int* __restrict__ tmp,
                                                   int* __restrict__ bsum, int N) {
    __shared__ int buf[1024];
    int t = threadIdx.x;
    int i = blockIdx.x * 1024 + t;
    int v = (i < N) ? deg[i] : 0;
    buf[t] = v;
    __syncthreads();
#pragma unroll
    for (int off = 1; off < 1024; off <<= 1) {
        int add = (t >= off) ? buf[t - off] : 0;
        __syncthreads();
        buf[t] += add;
        __syncthreads();
    }
    if (i < N) tmp[i] = buf[t];
    if (t == 1023) bsum[blockIdx.x] = buf[t];
}

// ---------------- scan of block sums (tiny, serial) ----------------
__global__ void scan_carry(int* __restrict__ bsum, int nb) {
    if (threadIdx.x == 0 && blockIdx.x == 0) {
        int run = 0;
        for (int b = 0; b < nb; b++) { int v = bsum[b]; bsum[b] = run; run += v; }
    }
}

// ---------------- apply carries -> exclusive offsets + cursor ----------------
__global__ void scan_apply(const int* __restrict__ deg, int* __restrict__ offs,
                           const int* __restrict__ bsum, int* __restrict__ cursor,
                           int N, int E) {
    int i = blockIdx.x * blockDim.x + threadIdx.x;
    if (i < N) {
        int excl = offs[i] - deg[i] + bsum[i >> 10];
        offs[i] = excl;
        cursor[i] = excl;
    }
    if (i == 0) offs[N] = E;
}

// ---------------- CSR fill ----------------
__global__ void fill_kernel(const int* __restrict__ adj, int* __restrict__ cursor,
                            int* __restrict__ csr, int E) {
    int i = blockIdx.x * blockDim.x + threadIdx.x;
    int stride = gridDim.x * blockDim.x;
    for (int e = i; e < E; e += stride) {
        int src = adj[e];
        int dst = adj[E + e];
        int pos = atomicAdd(&cursor[dst], 1);
        csr[pos] = src;
    }
}

// ---------------- gather + mean: one wave per destination node ----------------
__global__ __launch_bounds__(256) void gather_kernel(const float* __restrict__ x,
                                                     const int* __restrict__ offs,
                                                     const int* __restrict__ csr,
                                                     float* __restrict__ acc, int N) {
    int wv = blockIdx.x * (blockDim.x >> 6) + (threadIdx.x >> 6);
    wv = __builtin_amdgcn_readfirstlane(wv);
    if (wv >= N) return;
    int lane = threadIdx.x & 63;
    int beg = offs[wv];
    int end = offs[wv + 1];
    const float* xp = x + (size_t)lane * 4;
    float4 s = make_float4(0.f, 0.f, 0.f, 0.f);
    int j = beg;
    for (; j + 4 <= end; j += 4) {
        int n0 = csr[j + 0];
        int n1 = csr[j + 1];
        int n2 = csr[j + 2];
        int n3 = csr[j + 3];
        float4 v0 = *(const float4*)(xp + (size_t)n0 * D);
        float4 v1 = *(const float4*)(xp + (size_t)n1 * D);
        float4 v2 = *(const float4*)(xp + (size_t)n2 * D);
        float4 v3 = *(const float4*)(xp + (size_t)n3 * D);
        s.x += (v0.x + v1.x) + (v2.x + v3.x);
        s.y += (v0.y + v1.y) + (v2.y + v3.y);
        s.z += (v0.z + v1.z) + (v2.z + v3.z);
        s.w += (v0.w + v1.w) + (v2.w + v3.w);
    }
    for (; j < end; ++j) {
        int n0 = csr[j];
        float4 v0 = *(const float4*)(xp + (size_t)n0 * D);
        s.x += v0.x; s.y += v0.y; s.z += v0.z; s.w += v0.w;
    }
    float inv = 1.0f / fmaxf((float)(end - beg), 1.0f);
    s.x *= inv; s.y *= inv; s.z *= inv; s.w *= inv;
    *(float4*)(acc + (size_t)wv * D + lane * 4) = s;
}

// ---------------- W split into MFMA-fragment-ordered bf16 hi/lo ----------------
// Wf element (n,k) at: (( (n>>4)*16 + (k>>5) )*64 + ((n&15)|(((k>>3)&3)<<4)) )*8 + (k&7)
__global__ void wsplit_kernel(const float* __restrict__ W,
                              short* __restrict__ Wfh, short* __restrict__ Wfl) {
    int tid = blockIdx.x * blockDim.x + threadIdx.x;   // 131072 threads
    int k = tid >> 8;          // 0..511
    int n = tid & 255;         // 0..255
    float v = W[(size_t)k * D + n];
    unsigned short h = f2bf(v);
    unsigned short lo = f2bf(v - bf2f(h));
    int lane = (n & 15) | (((k >> 3) & 3) << 4);
    int idx = ((((n >> 4) << 4) + (k >> 5)) * 64 + lane) * 8 + (k & 7);
    Wfh[idx] = (short)h;
    Wfl[idx] = (short)lo;
}

// ---------------- MFMA bf16-split GEMM + bias + relu + L2 norm ----------------
// Block: 256 threads = 4 waves. Tile 64 rows x 256 cols, K=512, KS=32 (16 steps).
// Wave w owns cols [64w, 64w+64): 4 m-frags x 4 n-frags of 16x16.
// 3-term split: hi@Whi + hi@Wlo + lo@Whi  (error ~2^-17, << fp32-path absmax).
__global__ __launch_bounds__(256) void gemm_mfma(
        const float* __restrict__ x,
        const float* __restrict__ acc,
        const short* __restrict__ Wfh,
        const short* __restrict__ Wfl,
        const float* __restrict__ bias,
        float* __restrict__ out,
        int N) {
    // A tiles in LDS, bf16 hi/lo, row pitch 40 shorts (80B) to spread banks
    __shared__ short Ah[64][40];
    __shared__ short Al[64][40];
    __shared__ float ssbuf[4][64];

    int t = threadIdx.x;
    int w = t >> 6;        // wave 0..3
    int l = t & 63;        // lane
    int lg = l >> 4;       // 0..3 (k-chunk group / C row group)
    int li = l & 15;       // 0..15 (m-row for A, n-col for B/C)
    int row0 = blockIdx.x * 64;

    f32x4 acc_[4][4];
#pragma unroll
    for (int mi = 0; mi < 4; mi++)
#pragma unroll
        for (int ni = 0; ni < 4; ni++)
            acc_[mi][ni] = (f32x4){0.f, 0.f, 0.f, 0.f};

    // A staging assignment: thread covers row (t>>2), k-chunk (t&3)*8
    int srow = t >> 2;
    int skk = (t & 3) * 8;
    int gr = row0 + srow;
    int grc = gr < N ? gr : N - 1;

    for (int s = 0; s < 16; ++s) {
        int k0 = s * 32;
        // W fragment loads (global, L2-resident, coalesced 1KB/frag) — independent of LDS
        bf16x8 bh[4], bl[4];
#pragma unroll
        for (int ni = 0; ni < 4; ni++) {
            int n16 = w * 4 + ni;
            size_t off = ((size_t)(n16 * 16 + s) * 64 + l) * 8;
            bh[ni] = *(const bf16x8*)(Wfh + off);
            bl[ni] = *(const bf16x8*)(Wfl + off);
        }

        __syncthreads();   // prev-iter A-frag reads done
        {
            // stage A: 8 fp32 -> hi/lo bf16
            const float* srcp = (k0 < D)
                ? (x + (size_t)grc * D + k0 + skk)
                : (acc + (size_t)grc * D + (k0 - D) + skk);
            float4 v0 = *(const float4*)(srcp);
            float4 v1 = *(const float4*)(srcp + 4);
            float vv[8] = {v0.x, v0.y, v0.z, v0.w, v1.x, v1.y, v1.z, v1.w};
            bf16x8 hv, lv;
#pragma unroll
            for (int j = 0; j < 8; j++) {
                unsigned short h = f2bf(vv[j]);
                hv[j] = (short)h;
                lv[j] = (short)f2bf(vv[j] - bf2f(h));
            }
            *(bf16x8*)&Ah[srow][skk] = hv;
            *(bf16x8*)&Al[srow][skk] = lv;
        }
        __syncthreads();

        // A fragment loads from LDS
        bf16x8 ah[4], al[4];
#pragma unroll
        for (int mi = 0; mi < 4; mi++) {
            ah[mi] = *(const bf16x8*)&Ah[mi * 16 + li][lg * 8];
            al[mi] = *(const bf16x8*)&Al[mi * 16 + li][lg * 8];
        }

        // 48 MFMAs: all three split terms accumulate into the same acc
#pragma unroll
        for (int mi = 0; mi < 4; mi++)
#pragma unroll
            for (int ni = 0; ni < 4; ni++) {
                acc_[mi][ni] = __builtin_amdgcn_mfma_f32_16x16x32_bf16(ah[mi], bh[ni], acc_[mi][ni], 0, 0, 0);
                acc_[mi][ni] = __builtin_amdgcn_mfma_f32_16x16x32_bf16(ah[mi], bl[ni], acc_[mi][ni], 0, 0, 0);
                acc_[mi][ni] = __builtin_amdgcn_mfma_f32_16x16x32_bf16(al[mi], bh[ni], acc_[mi][ni], 0, 0, 0);
            }
    }

    // ---- epilogue: bias + relu + cross-wave row L2 norm + store ----
    float bv[4];
#pragma unroll
    for (int ni = 0; ni < 4; ni++) bv[ni] = bias[w * 64 + ni * 16 + li];

#pragma unroll
    for (int mi = 0; mi < 4; mi++) {
#pragma unroll
        for (int reg = 0; reg < 4; reg++) {
            float sp = 0.f;
#pragma unroll
            for (int ni = 0; ni < 4; ni++) {
                float v = acc_[mi][ni][reg] + bv[ni];
                v = fmaxf(v, 0.f);
                acc_[mi][ni][reg] = v;
                sp += v * v;
            }
            sp += __shfl_xor(sp, 1);
            sp += __shfl_xor(sp, 2);
            sp += __shfl_xor(sp, 4);
            sp += __shfl_xor(sp, 8);
            if (li == 0) ssbuf[w][mi * 16 + lg * 4 + reg] = sp;
        }
    }
    __syncthreads();
#pragma unroll
    for (int mi = 0; mi < 4; mi++) {
#pragma unroll
        for (int reg = 0; reg < 4; reg++) {
            int r = mi * 16 + lg * 4 + reg;
            float tot = ssbuf[0][r] + ssbuf[1][r] + ssbuf[2][r] + ssbuf[3][r];
            float inv = 1.0f / fmaxf(sqrtf(tot), EPS);
            int grr = row0 + r;
            if (grr < N) {
#pragma unroll
                for (int ni = 0; ni < 4; ni++)
                    out[(size_t)grr * D + w * 64 + ni * 16 + li] = acc_[mi][ni][reg] * inv;
            }
        }
    }
}

// ---------------- legacy fallback (tiny ws): atomic scatter + fp32 gemm ----------------
__global__ void zero_floats(float* __restrict__ a, size_t n4) {
    size_t i = (size_t)blockIdx.x * blockDim.x + threadIdx.x;
    size_t stride = (size_t)gridDim.x * blockDim.x;
    float4* a4 = (float4*)a;
    float4 z = make_float4(0.f, 0.f, 0.f, 0.f);
    for (size_t k = i; k < n4; k += stride) a4[k] = z;
}

__global__ void scatter_kernel(const float* __restrict__ x, const int* __restrict__ adj,
                               float* __restrict__ acc, float* __restrict__ deg, int E) {
    int wave = blockIdx.x * (blockDim.x >> 6) + (threadIdx.x >> 6);
    int lane = threadIdx.x & 63;
    int nw = gridDim.x * (blockDim.x >> 6);
    for (int e = wave; e < E; e += nw) {
        int src = adj[e];
        int dst = adj[E + e];
        float4 v = *(const float4*)(x + (size_t)src * D + lane * 4);
        float* p = acc + (size_t)dst * D + lane * 4;
        atomicAdd(p + 0, v.x);
        atomicAdd(p + 1, v.y);
        atomicAdd(p + 2, v.z);
        atomicAdd(p + 3, v.w);
        if (lane == 0) atomicAdd(deg + dst, 1.0f);
    }
}

__global__ void mean_kernel(float* __restrict__ acc, const float* __restrict__ deg, int N) {
    int wv = blockIdx.x * (blockDim.x >> 6) + (threadIdx.x >> 6);
    if (wv >= N) return;
    int lane = threadIdx.x & 63;
    float inv = 1.0f / fmaxf(deg[wv], 1.0f);
    float4* p = (float4*)(acc + (size_t)wv * D) + lane;
    float4 v = *p;
    v.x *= inv; v.y *= inv; v.z *= inv; v.w *= inv;
    *p = v;
}

__global__ __launch_bounds__(256) void gemm_fp32(
        const float* __restrict__ x, const float* __restrict__ acc,
        const float* __restrict__ W, const float* __restrict__ bias,
        float* __restrict__ out, int N) {
    __shared__ float Ast[32][64];
    __shared__ float Ws[32][D];
    int t = threadIdx.x;
    int row0 = blockIdx.x * 64;
    int tx = t & 15, ty = t >> 4;
    float accr[4][16];
#pragma unroll
    for (int i = 0; i < 4; i++)
#pragma unroll
        for (int j = 0; j < 16; j++) accr[i][j] = 0.f;
    int arow = t >> 3, akv = t & 7, wc = t & 63, wk0 = t >> 6;
    for (int k0 = 0; k0 < 2 * D; k0 += 32) {
        __syncthreads();
#pragma unroll
        for (int rr = 0; rr < 2; rr++) {
            int rl = arow + rr * 32;
            int gr = row0 + rl;
            int grc = gr < N ? gr : N - 1;
            float4 v = (k0 < D) ? *(const float4*)(x + (size_t)grc * D + k0 + akv * 4)
                                : *(const float4*)(acc + (size_t)grc * D + (k0 - D) + akv * 4);
            Ast[akv * 4 + 0][rl] = v.x; Ast[akv * 4 + 1][rl] = v.y;
            Ast[akv * 4 + 2][rl] = v.z; Ast[akv * 4 + 3][rl] = v.w;
        }
#pragma unroll
        for (int kk = 0; kk < 8; kk++) {
            int kr = wk0 + kk * 4;
            *(float4*)(&Ws[kr][wc * 4]) = *(const float4*)(W + (size_t)(k0 + kr) * D + wc * 4);
        }
        __syncthreads();
#pragma unroll
        for (int k = 0; k < 32; k++) {
            float4 a4 = *(const float4*)(&Ast[k][ty * 4]);
            float av[4] = {a4.x, a4.y, a4.z, a4.w};
#pragma unroll
            for (int j2 = 0; j2 < 4; j2++) {
                float4 w4 = *(const float4*)(&Ws[k][j2 * 64 + tx * 4]);
                float wv[4] = {w4.x, w4.y, w4.z, w4.w};
#pragma unroll
                for (int i = 0; i < 4; i++)
#pragma unroll
                    for (int j = 0; j < 4; j++)
                        accr[i][j2 * 4 + j] += av[i] * wv[j];
            }
        }
    }
    float bval[16];
#pragma unroll
    for (int j2 = 0; j2 < 4; j2++) {
        float4 b4 = *(const float4*)(bias + j2 * 64 + tx * 4);
        bval[j2 * 4 + 0] = b4.x; bval[j2 * 4 + 1] = b4.y;
        bval[j2 * 4 + 2] = b4.z; bval[j2 * 4 + 3] = b4.w;
    }
#pragma unroll
    for (int i = 0; i < 4; i++) {
        float ss = 0.f;
#pragma unroll
        for (int j = 0; j < 16; j++) {
            float v = accr[i][j] + bval[j];
            v = fmaxf(v, 0.f);
            accr[i][j] = v;
            ss += v * v;
        }
        ss += __shfl_xor(ss, 1); ss += __shfl_xor(ss, 2);
        ss += __shfl_xor(ss, 4); ss += __shfl_xor(ss, 8);
        float inv = 1.0f / fmaxf(sqrtf(ss), EPS);
        int gr = row0 + ty * 4 + i;
        if (gr < N) {
#pragma unroll
            for (int j2 = 0; j2 < 4; j2++) {
                float4 o;
                o.x = accr[i][j2 * 4 + 0] * inv; o.y = accr[i][j2 * 4 + 1] * inv;
                o.z = accr[i][j2 * 4 + 2] * inv; o.w = accr[i][j2 * 4 + 3] * inv;
                *(float4*)(out + (size_t)gr * D + j2 * 64 + tx * 4) = o;
            }
        }
    }
}

extern "C" void kernel_launch(void* const* d_in, const int* in_sizes, int n_in,
                              void* d_out, int out_size, void* d_ws, size_t ws_size,
                              hipStream_t stream) {
    const float* x = (const float*)d_in[0];
    const int* adj = (const int*)d_in[1];
    const float* W = (const float*)d_in[2];
    const float* b = (const float*)d_in[3];
    float* out = (float*)d_out;

    int N = in_sizes[0] / D;    // 50000
    int E = in_sizes[1] / 2;    // 800000

    size_t accBytes = (size_t)N * D * sizeof(float);
    size_t nInts = (size_t)3 * N + 1 + E + 64;                 // deg|offs|cursor|csr|bsum
    size_t intBytes = nInts * sizeof(int);
    size_t wElems = (size_t)2 * D * D;                         // 512*256
    size_t wfBytes = 2 * wElems * sizeof(short);               // hi+lo

    int gb = (N + 63) / 64;                 // 782 gemm blocks
    int gatherBlocks = (N + 3) / 4;
    int nbScan = (N + 1023) / 1024;
    int wsplitBlocks = (int)(wElems / 256);

    auto run_csr_mfma = [&](float* acc, char* intBase) {
        int* deg = (int*)intBase;
        int* offs = deg + N;          // N+1
        int* cursor = offs + N + 1;
        int* csr = cursor + N;
        int* bsum = csr + E;          // 64
        uintptr_t wfp = ((uintptr_t)(bsum + 64) + 15) & ~(uintptr_t)15;
        short* Wfh = (short*)wfp;
        short* Wfl = Wfh + wElems;
        zero_ints<<<(N + 255) / 256, 256, 0, stream>>>(deg, N);
        hist_kernel<<<1024, 256, 0, stream>>>(adj, deg, E);
        scan_local<<<nbScan, 1024, 0, stream>>>(deg, offs, bsum, N);
        scan_carry<<<1, 64, 0, stream>>>(bsum, nbScan);
        scan_apply<<<(N + 255) / 256, 256, 0, stream>>>(deg, offs, bsum, cursor, N, E);
        fill_kernel<<<1024, 256, 0, stream>>>(adj, cursor, csr, E);
        gather_kernel<<<gatherBlocks, 256, 0, stream>>>(x, offs, csr, acc, N);
        wsplit_kernel<<<wsplitBlocks, 256, 0, stream>>>(W, Wfh, Wfl);
        gemm_mfma<<<gb, 256, 0, stream>>>(x, acc, Wfh, Wfl, b, out, N);
    };

    if (ws_size >= accBytes + intBytes + wfBytes + 16) {
        // Tier B: acc in workspace
        run_csr_mfma((float*)d_ws, (char*)d_ws + accBytes);
    } else if (ws_size >= intBytes + wfBytes + 16) {
        // Tier C: acc in d_out (each gemm block reads only rows it later writes)
        run_csr_mfma((float*)d_out, (char*)d_ws);
    } else {
        // Tier D: legacy atomic path
        float* acc = (float*)d_out;
        float* deg = (float*)d_ws;
        zero_floats<<<2048, 256, 0, stream>>>(acc, (size_t)N * D / 4);
        zero_floats<<<64, 256, 0, stream>>>(deg, (size_t)N / 4);
        scatter_kernel<<<2048, 256, 0, stream>>>(x, adj, acc, deg, E);
        mean_kernel<<<gatherBlocks, 256, 0, stream>>>(acc, deg, N);
        gemm_fp32<<<gb, 256, 0, stream>>>(x, acc, W, b, out, N);
    }
}

// Round 6
// 337.394 us; speedup vs baseline: 9.0366x; 1.1045x over previous
//
#include <hip/hip_runtime.h>
#include <hip/hip_fp16.h>
#include <math.h>

#define D 256
#define EPS 1e-12f

typedef __attribute__((ext_vector_type(8))) short bf16x8;
typedef __attribute__((ext_vector_type(4))) float f32x4;

// ---- fp32 -> bf16 split helpers (RNE) ----
__device__ __forceinline__ unsigned short f2bf(float f) {
    unsigned int u = __builtin_bit_cast(unsigned int, f);
    unsigned int r = u + 0x7fffu + ((u >> 16) & 1u);
    return (unsigned short)(r >> 16);
}
__device__ __forceinline__ float bf2f(unsigned short s) {
    unsigned int u = ((unsigned int)s) << 16;
    return __builtin_bit_cast(float, u);
}

// ---------------- degree histogram ----------------
__global__ void hist_kernel(const int* __restrict__ adj, int* __restrict__ deg, int E) {
    int i = blockIdx.x * blockDim.x + threadIdx.x;
    int stride = gridDim.x * blockDim.x;
    for (int e = i; e < E; e += stride) atomicAdd(&deg[adj[E + e]], 1);
}

// ---------------- multi-block scan: local inclusive ----------------
__global__ __launch_bounds__(1024) void scan_local(const int* __restrict__ deg,
                                                   int* __restrict__ tmp,
                                                   int* __restrict__ bsum, int N) {
    __shared__ int buf[1024];
    int t = threadIdx.x;
    int i = blockIdx.x * 1024 + t;
    int v = (i < N) ? deg[i] : 0;
    buf[t] = v;
    __syncthreads();
#pragma unroll
    for (int off = 1; off < 1024; off <<= 1) {
        int add = (t >= off) ? buf[t - off] : 0;
        __syncthreads();
        buf[t] += add;
        __syncthreads();
    }
    if (i < N) tmp[i] = buf[t];
    if (t == 1023) bsum[blockIdx.x] = buf[t];
}

// ---------------- scan of block sums (tiny, serial) ----------------
__global__ void scan_carry(int* __restrict__ bsum, int nb) {
    if (threadIdx.x == 0 && blockIdx.x == 0) {
        int run = 0;
        for (int b = 0; b < nb; b++) { int v = bsum[b]; bsum[b] = run; run += v; }
    }
}

// ---------------- apply carries -> exclusive offsets + cursor ----------------
__global__ void scan_apply(const int* __restrict__ deg, int* __restrict__ offs,
                           const int* __restrict__ bsum, int* __restrict__ cursor,
                           int N, int E) {
    int i = blockIdx.x * blockDim.x + threadIdx.x;
    if (i < N) {
        int excl = offs[i] - deg[i] + bsum[i >> 10];
        offs[i] = excl;
        cursor[i] = excl;
    }
    if (i == 0) offs[N] = E;
}

// ---------------- CSR fill ----------------
__global__ void fill_kernel(const int* __restrict__ adj, int* __restrict__ cursor,
                            int* __restrict__ csr, int E) {
    int i = blockIdx.x * blockDim.x + threadIdx.x;
    int stride = gridDim.x * blockDim.x;
    for (int e = i; e < E; e += stride) {
        int src = adj[e];
        int dst = adj[E + e];
        int pos = atomicAdd(&cursor[dst], 1);
        csr[pos] = src;
    }
}

// ---------------- x -> fp16 table (halves gather traffic) ----------------
__global__ void xhalf_kernel(const float* __restrict__ x, __half* __restrict__ xh, int total8) {
    int i = blockIdx.x * blockDim.x + threadIdx.x;   // 8 elems per thread
    if (i >= total8) return;
    const float4* p = (const float4*)x + (size_t)i * 2;
    float4 v0 = p[0];
    float4 v1 = p[1];
    __half2 h[4];
    h[0] = __floats2half2_rn(v0.x, v0.y);
    h[1] = __floats2half2_rn(v0.z, v0.w);
    h[2] = __floats2half2_rn(v1.x, v1.y);
    h[3] = __floats2half2_rn(v1.z, v1.w);
    *(uint4*)(xh + (size_t)i * 8) = *(const uint4*)h;
}

// ---------------- gather + mean: one wave per destination node ----------------
// fp16 rows (512 B): lane l covers elems [4l, 4l+4). 8 rows in flight.
__global__ __launch_bounds__(256) void gather_kernel(const __half* __restrict__ xh,
                                                     const int* __restrict__ offs,
                                                     const int* __restrict__ csr,
                                                     float* __restrict__ acc, int N) {
    int wv = blockIdx.x * (blockDim.x >> 6) + (threadIdx.x >> 6);
    wv = __builtin_amdgcn_readfirstlane(wv);
    if (wv >= N) return;
    int lane = threadIdx.x & 63;
    int beg = offs[wv];
    int end = offs[wv + 1];
    const __half* xp = xh + (size_t)lane * 4;
    float s0 = 0.f, s1 = 0.f, s2 = 0.f, s3 = 0.f;
    int j = beg;
    for (; j + 8 <= end; j += 8) {
        int n[8];
#pragma unroll
        for (int u = 0; u < 8; u++) n[u] = csr[j + u];
        uint2 r[8];
#pragma unroll
        for (int u = 0; u < 8; u++) r[u] = *(const uint2*)(xp + (size_t)n[u] * D);
#pragma unroll
        for (int u = 0; u < 8; u++) {
            float2 fa = __half22float2(__builtin_bit_cast(__half2, r[u].x));
            float2 fb = __half22float2(__builtin_bit_cast(__half2, r[u].y));
            s0 += fa.x; s1 += fa.y; s2 += fb.x; s3 += fb.y;
        }
    }
    for (; j < end; ++j) {
        uint2 r = *(const uint2*)(xp + (size_t)csr[j] * D);
        float2 fa = __half22float2(__builtin_bit_cast(__half2, r.x));
        float2 fb = __half22float2(__builtin_bit_cast(__half2, r.y));
        s0 += fa.x; s1 += fa.y; s2 += fb.x; s3 += fb.y;
    }
    float inv = 1.0f / fmaxf((float)(end - beg), 1.0f);
    float4 o = make_float4(s0 * inv, s1 * inv, s2 * inv, s3 * inv);
    *(float4*)(acc + (size_t)wv * D + lane * 4) = o;
}

// ---------------- W split into MFMA-fragment-ordered bf16 hi/lo ----------------
__global__ void wsplit_kernel(const float* __restrict__ W,
                              short* __restrict__ Wfh, short* __restrict__ Wfl) {
    int tid = blockIdx.x * blockDim.x + threadIdx.x;   // 131072 threads
    int k = tid >> 8;          // 0..511
    int n = tid & 255;         // 0..255
    float v = W[(size_t)k * D + n];
    unsigned short h = f2bf(v);
    unsigned short lo = f2bf(v - bf2f(h));
    int lane = (n & 15) | (((k >> 3) & 3) << 4);
    int idx = ((((n >> 4) << 4) + (k >> 5)) * 64 + lane) * 8 + (k & 7);
    Wfh[idx] = (short)h;
    Wfl[idx] = (short)lo;
}

// ---------------- MFMA bf16-split GEMM + bias + relu + L2 norm ----------------
// Block: 256 threads = 4 waves. Tile 64 rows x 256 cols, K=512, KS=32 (16 steps).
__global__ __launch_bounds__(256) void gemm_mfma(
        const float* __restrict__ x,
        const float* __restrict__ acc,
        const short* __restrict__ Wfh,
        const short* __restrict__ Wfl,
        const float* __restrict__ bias,
        float* __restrict__ out,
        int N) {
    __shared__ short Ah[64][40];   // pitch 40 shorts (80B) spreads banks
    __shared__ short Al[64][40];
    __shared__ float ssbuf[4][64];

    int t = threadIdx.x;
    int w = t >> 6;
    int l = t & 63;
    int lg = l >> 4;
    int li = l & 15;
    int row0 = blockIdx.x * 64;

    f32x4 acc_[4][4];
#pragma unroll
    for (int mi = 0; mi < 4; mi++)
#pragma unroll
        for (int ni = 0; ni < 4; ni++)
            acc_[mi][ni] = (f32x4){0.f, 0.f, 0.f, 0.f};

    int srow = t >> 2;
    int skk = (t & 3) * 8;
    int gr = row0 + srow;
    int grc = gr < N ? gr : N - 1;

    for (int s = 0; s < 16; ++s) {
        int k0 = s * 32;
        bf16x8 bh[4], bl[4];
#pragma unroll
        for (int ni = 0; ni < 4; ni++) {
            int n16 = w * 4 + ni;
            size_t off = ((size_t)(n16 * 16 + s) * 64 + l) * 8;
            bh[ni] = *(const bf16x8*)(Wfh + off);
            bl[ni] = *(const bf16x8*)(Wfl + off);
        }

        __syncthreads();
        {
            const float* srcp = (k0 < D)
                ? (x + (size_t)grc * D + k0 + skk)
                : (acc + (size_t)grc * D + (k0 - D) + skk);
            float4 v0 = *(const float4*)(srcp);
            float4 v1 = *(const float4*)(srcp + 4);
            float vv[8] = {v0.x, v0.y, v0.z, v0.w, v1.x, v1.y, v1.z, v1.w};
            bf16x8 hv, lv;
#pragma unroll
            for (int j = 0; j < 8; j++) {
                unsigned short h = f2bf(vv[j]);
                hv[j] = (short)h;
                lv[j] = (short)f2bf(vv[j] - bf2f(h));
            }
            *(bf16x8*)&Ah[srow][skk] = hv;
            *(bf16x8*)&Al[srow][skk] = lv;
        }
        __syncthreads();

        bf16x8 ah[4], al[4];
#pragma unroll
        for (int mi = 0; mi < 4; mi++) {
            ah[mi] = *(const bf16x8*)&Ah[mi * 16 + li][lg * 8];
            al[mi] = *(const bf16x8*)&Al[mi * 16 + li][lg * 8];
        }

#pragma unroll
        for (int mi = 0; mi < 4; mi++)
#pragma unroll
            for (int ni = 0; ni < 4; ni++) {
                acc_[mi][ni] = __builtin_amdgcn_mfma_f32_16x16x32_bf16(ah[mi], bh[ni], acc_[mi][ni], 0, 0, 0);
                acc_[mi][ni] = __builtin_amdgcn_mfma_f32_16x16x32_bf16(ah[mi], bl[ni], acc_[mi][ni], 0, 0, 0);
                acc_[mi][ni] = __builtin_amdgcn_mfma_f32_16x16x32_bf16(al[mi], bh[ni], acc_[mi][ni], 0, 0, 0);
            }
    }

    float bv[4];
#pragma unroll
    for (int ni = 0; ni < 4; ni++) bv[ni] = bias[w * 64 + ni * 16 + li];

#pragma unroll
    for (int mi = 0; mi < 4; mi++) {
#pragma unroll
        for (int reg = 0; reg < 4; reg++) {
            float sp = 0.f;
#pragma unroll
            for (int ni = 0; ni < 4; ni++) {
                float v = acc_[mi][ni][reg] + bv[ni];
                v = fmaxf(v, 0.f);
                acc_[mi][ni][reg] = v;
                sp += v * v;
            }
            sp += __shfl_xor(sp, 1);
            sp += __shfl_xor(sp, 2);
            sp += __shfl_xor(sp, 4);
            sp += __shfl_xor(sp, 8);
            if (li == 0) ssbuf[w][mi * 16 + lg * 4 + reg] = sp;
        }
    }
    __syncthreads();
#pragma unroll
    for (int mi = 0; mi < 4; mi++) {
#pragma unroll
        for (int reg = 0; reg < 4; reg++) {
            int r = mi * 16 + lg * 4 + reg;
            float tot = ssbuf[0][r] + ssbuf[1][r] + ssbuf[2][r] + ssbuf[3][r];
            float inv = 1.0f / fmaxf(sqrtf(tot), EPS);
            int grr = row0 + r;
            if (grr < N) {
#pragma unroll
                for (int ni = 0; ni < 4; ni++)
                    out[(size_t)grr * D + w * 64 + ni * 16 + li] = acc_[mi][ni][reg] * inv;
            }
        }
    }
}

// ---------------- legacy fallback (tiny ws) ----------------
__global__ void zero_floats(float* __restrict__ a, size_t n4) {
    size_t i = (size_t)blockIdx.x * blockDim.x + threadIdx.x;
    size_t stride = (size_t)gridDim.x * blockDim.x;
    float4* a4 = (float4*)a;
    float4 z = make_float4(0.f, 0.f, 0.f, 0.f);
    for (size_t k = i; k < n4; k += stride) a4[k] = z;
}

__global__ void scatter_kernel(const float* __restrict__ x, const int* __restrict__ adj,
                               float* __restrict__ acc, float* __restrict__ deg, int E) {
    int wave = blockIdx.x * (blockDim.x >> 6) + (threadIdx.x >> 6);
    int lane = threadIdx.x & 63;
    int nw = gridDim.x * (blockDim.x >> 6);
    for (int e = wave; e < E; e += nw) {
        int src = adj[e];
        int dst = adj[E + e];
        float4 v = *(const float4*)(x + (size_t)src * D + lane * 4);
        float* p = acc + (size_t)dst * D + lane * 4;
        atomicAdd(p + 0, v.x);
        atomicAdd(p + 1, v.y);
        atomicAdd(p + 2, v.z);
        atomicAdd(p + 3, v.w);
        if (lane == 0) atomicAdd(deg + dst, 1.0f);
    }
}

__global__ void mean_kernel(float* __restrict__ acc, const float* __restrict__ deg, int N) {
    int wv = blockIdx.x * (blockDim.x >> 6) + (threadIdx.x >> 6);
    if (wv >= N) return;
    int lane = threadIdx.x & 63;
    float inv = 1.0f / fmaxf(deg[wv], 1.0f);
    float4* p = (float4*)(acc + (size_t)wv * D) + lane;
    float4 v = *p;
    v.x *= inv; v.y *= inv; v.z *= inv; v.w *= inv;
    *p = v;
}

__global__ __launch_bounds__(256) void gemm_fp32(
        const float* __restrict__ x, const float* __restrict__ acc,
        const float* __restrict__ W, const float* __restrict__ bias,
        float* __restrict__ out, int N) {
    __shared__ float Ast[32][64];
    __shared__ float Ws[32][D];
    int t = threadIdx.x;
    int row0 = blockIdx.x * 64;
    int tx = t & 15, ty = t >> 4;
    float accr[4][16];
#pragma unroll
    for (int i = 0; i < 4; i++)
#pragma unroll
        for (int j = 0; j < 16; j++) accr[i][j] = 0.f;
    int arow = t >> 3, akv = t & 7, wc = t & 63, wk0 = t >> 6;
    for (int k0 = 0; k0 < 2 * D; k0 += 32) {
        __syncthreads();
#pragma unroll
        for (int rr = 0; rr < 2; rr++) {
            int rl = arow + rr * 32;
            int gr = row0 + rl;
            int grc = gr < N ? gr : N - 1;
            float4 v = (k0 < D) ? *(const float4*)(x + (size_t)grc * D + k0 + akv * 4)
                                : *(const float4*)(acc + (size_t)grc * D + (k0 - D) + akv * 4);
            Ast[akv * 4 + 0][rl] = v.x; Ast[akv * 4 + 1][rl] = v.y;
            Ast[akv * 4 + 2][rl] = v.z; Ast[akv * 4 + 3][rl] = v.w;
        }
#pragma unroll
        for (int kk = 0; kk < 8; kk++) {
            int kr = wk0 + kk * 4;
            *(float4*)(&Ws[kr][wc * 4]) = *(const float4*)(W + (size_t)(k0 + kr) * D + wc * 4);
        }
        __syncthreads();
#pragma unroll
        for (int k = 0; k < 32; k++) {
            float4 a4 = *(const float4*)(&Ast[k][ty * 4]);
            float av[4] = {a4.x, a4.y, a4.z, a4.w};
#pragma unroll
            for (int j2 = 0; j2 < 4; j2++) {
                float4 w4 = *(const float4*)(&Ws[k][j2 * 64 + tx * 4]);
                float wv[4] = {w4.x, w4.y, w4.z, w4.w};
#pragma unroll
                for (int i = 0; i < 4; i++)
#pragma unroll
                    for (int j = 0; j < 4; j++)
                        accr[i][j2 * 4 + j] += av[i] * wv[j];
            }
        }
    }
    float bval[16];
#pragma unroll
    for (int j2 = 0; j2 < 4; j2++) {
        float4 b4 = *(const float4*)(bias + j2 * 64 + tx * 4);
        bval[j2 * 4 + 0] = b4.x; bval[j2 * 4 + 1] = b4.y;
        bval[j2 * 4 + 2] = b4.z; bval[j2 * 4 + 3] = b4.w;
    }
#pragma unroll
    for (int i = 0; i < 4; i++) {
        float ss = 0.f;
#pragma unroll
        for (int j = 0; j < 16; j++) {
            float v = accr[i][j] + bval[j];
            v = fmaxf(v, 0.f);
            accr[i][j] = v;
            ss += v * v;
        }
        ss += __shfl_xor(ss, 1); ss += __shfl_xor(ss, 2);
        ss += __shfl_xor(ss, 4); ss += __shfl_xor(ss, 8);
        float inv = 1.0f / fmaxf(sqrtf(ss), EPS);
        int gr = row0 + ty * 4 + i;
        if (gr < N) {
#pragma unroll
            for (int j2 = 0; j2 < 4; j2++) {
                float4 o;
                o.x = accr[i][j2 * 4 + 0] * inv; o.y = accr[i][j2 * 4 + 1] * inv;
                o.z = accr[i][j2 * 4 + 2] * inv; o.w = accr[i][j2 * 4 + 3] * inv;
                *(float4*)(out + (size_t)gr * D + j2 * 64 + tx * 4) = o;
            }
        }
    }
}

extern "C" void kernel_launch(void* const* d_in, const int* in_sizes, int n_in,
                              void* d_out, int out_size, void* d_ws, size_t ws_size,
                              hipStream_t stream) {
    const float* x = (const float*)d_in[0];
    const int* adj = (const int*)d_in[1];
    const float* W = (const float*)d_in[2];
    const float* b = (const float*)d_in[3];
    float* out = (float*)d_out;

    int N = in_sizes[0] / D;    // 50000
    int E = in_sizes[1] / 2;    // 800000

    size_t accBytes = (size_t)N * D * sizeof(float);
    size_t nInts = (size_t)3 * N + 1 + E + 64;                 // deg|offs|cursor|csr|bsum
    size_t intBytes = nInts * sizeof(int);
    size_t wElems = (size_t)2 * D * D;
    size_t wfBytes = 2 * wElems * sizeof(short);
    size_t xhBytes = (size_t)N * D * sizeof(__half);

    int gb = (N + 63) / 64;
    int gatherBlocks = (N + 3) / 4;
    int nbScan = (N + 1023) / 1024;
    int wsplitBlocks = (int)(wElems / 256);
    int xh8 = N * D / 8;

    auto run_csr_mfma = [&](float* acc, char* base) {
        int* deg = (int*)base;
        int* offs = deg + N;          // N+1
        int* cursor = offs + N + 1;
        int* csr = cursor + N;
        int* bsum = csr + E;          // 64
        uintptr_t p2 = ((uintptr_t)(bsum + 64) + 15) & ~(uintptr_t)15;
        short* Wfh = (short*)p2;
        short* Wfl = Wfh + wElems;
        __half* xh = (__half*)(Wfl + wElems);
        hipMemsetAsync(deg, 0, (size_t)N * sizeof(int), stream);
        hist_kernel<<<1024, 256, 0, stream>>>(adj, deg, E);
        xhalf_kernel<<<(xh8 + 255) / 256, 256, 0, stream>>>(x, xh, xh8);
        scan_local<<<nbScan, 1024, 0, stream>>>(deg, offs, bsum, N);
        scan_carry<<<1, 64, 0, stream>>>(bsum, nbScan);
        scan_apply<<<(N + 255) / 256, 256, 0, stream>>>(deg, offs, bsum, cursor, N, E);
        fill_kernel<<<1024, 256, 0, stream>>>(adj, cursor, csr, E);
        gather_kernel<<<gatherBlocks, 256, 0, stream>>>(xh, offs, csr, acc, N);
        wsplit_kernel<<<wsplitBlocks, 256, 0, stream>>>(W, Wfh, Wfl);
        gemm_mfma<<<gb, 256, 0, stream>>>(x, acc, Wfh, Wfl, b, out, N);
    };

    if (ws_size >= accBytes + intBytes + wfBytes + xhBytes + 32) {
        run_csr_mfma((float*)d_ws, (char*)d_ws + accBytes);
    } else if (ws_size >= intBytes + wfBytes + xhBytes + 32) {
        // acc in d_out (each gemm block reads only rows it later writes)
        run_csr_mfma((float*)d_out, (char*)d_ws);
    } else {
        // legacy atomic path
        float* acc = (float*)d_out;
        float* deg = (float*)d_ws;
        zero_floats<<<2048, 256, 0, stream>>>(acc, (size_t)N * D / 4);
        zero_floats<<<64, 256, 0, stream>>>(deg, (size_t)N / 4);
        scatter_kernel<<<2048, 256, 0, stream>>>(x, adj, acc, deg, E);
        mean_kernel<<<gatherBlocks, 256, 0, stream>>>(acc, deg, N);
        gemm_fp32<<<gb, 256, 0, stream>>>(x, acc, W, b, out, N);
    }
}